// Round 12
// baseline (244.648 us; speedup 1.0000x reference)
//
#include <hip/hip_runtime.h>
#include <math.h>

// Problem constants
#define NN 2048      // nodes per modality
#define TWO_N 4096   // total nodes
#define BB 4         // batch
#define CC 64        // input feature dim
#define HD 128       // hidden dim
#define CANDCAP 32   // max top-k candidates per row after f32 margin filter
#define KC 32        // gemm K-chunk
#define NE4 (4 * NN) // materialized hyperedges (inter edges handled inline in k_node)

// Layouts: y/z are v-major [v][b][f] (row r' = v*4+b); u is [e][b][f], e in [0,4N).

// ---------------------------------------------------------------------------
// 1) batch-mean + L2-normalize.
// ---------------------------------------------------------------------------
__global__ void k_mean_norm(const float* __restrict__ f1, const float* __restrict__ f2,
                            float* __restrict__ g32T, double* __restrict__ gR64) {
    int n = blockIdx.x;           // node
    int m = blockIdx.y;           // modality
    int c = threadIdx.x;          // 64 threads = 1 wave
    const float* f = m ? f2 : f1;
    double s = 0.0;
    for (int b = 0; b < BB; ++b) s += (double)f[((size_t)(b * NN) + n) * CC + c];
    double mean = s * 0.25;
    double sq = mean * mean;
    for (int d = 32; d >= 1; d >>= 1) sq += __shfl_xor(sq, d);
    double norm = sqrt(sq);
    if (norm < 1e-12) norm = 1e-12;
    double g = mean / norm;
    g32T[((size_t)m * CC + c) * NN + n] = (float)g;
    gR64[((size_t)m * NN + n) * CC + c] = g;
}

// ---------------------------------------------------------------------------
// 2) f32 sims GEMM: sims[m] = G32 * G32^T  (2048x2048, K=64).
// ---------------------------------------------------------------------------
__global__ void __launch_bounds__(256)
k_sims(const float* __restrict__ g32T, float* __restrict__ sims) {
    __shared__ float As[CC][64];   // As[k][r], 16 KB
    __shared__ float Bs[CC][64];   // Bs[k][j], 16 KB
    int m  = blockIdx.y;
    int bi = blockIdx.x >> 5, bj = blockIdx.x & 31;
    int i0 = bi * 64, j0 = bj * 64;
    const float* g = g32T + (size_t)m * CC * NN;
    int tid = threadIdx.x;
    #pragma unroll
    for (int q = 0; q < 16; ++q) {
        int idx = q * 256 + tid;
        int k = idx >> 6, r = idx & 63;
        As[k][r] = g[(size_t)k * NN + i0 + r];
        Bs[k][r] = g[(size_t)k * NN + j0 + r];
    }
    __syncthreads();
    int tr = tid >> 4, tc = tid & 15;
    float acc[4][4] = {{0.f}};
    #pragma unroll
    for (int k = 0; k < CC; ++k) {
        float4 a = *((const float4*)&As[k][tr << 2]);
        float4 b = *((const float4*)&Bs[k][tc << 2]);
        acc[0][0] += a.x * b.x; acc[0][1] += a.x * b.y; acc[0][2] += a.x * b.z; acc[0][3] += a.x * b.w;
        acc[1][0] += a.y * b.x; acc[1][1] += a.y * b.y; acc[1][2] += a.y * b.z; acc[1][3] += a.y * b.w;
        acc[2][0] += a.z * b.x; acc[2][1] += a.z * b.y; acc[2][2] += a.z * b.z; acc[2][3] += a.z * b.w;
        acc[3][0] += a.w * b.x; acc[3][1] += a.w * b.y; acc[3][2] += a.w * b.z; acc[3][3] += a.w * b.w;
    }
    float* srow = sims + (size_t)m * NN * NN;
    #pragma unroll
    for (int x = 0; x < 4; ++x) {
        float4 v = make_float4(acc[x][0], acc[x][1], acc[x][2], acc[x][3]);
        *((float4*)&srow[(size_t)(i0 + (tr << 2) + x) * NN + j0 + (tc << 2)]) = v;
    }
}

// ---------------------------------------------------------------------------
// 3) f32 threshold + margin candidate capture (binary-search ballot count).
//    R10-proven structure: candidates to GLOBAL cand/cntb; DV[row]=1 init.
//    thr = lo - 1e-5 <= vK_f32 - 2*eps => cand superset of true f64 top-K.
// ---------------------------------------------------------------------------
__global__ void __launch_bounds__(512)
k_select(const float* __restrict__ sims, int* __restrict__ cand, int* __restrict__ cntb,
         int* __restrict__ DV) {
    int wave = threadIdx.x >> 6, lane = threadIdx.x & 63;
    int row = blockIdx.x * 8 + wave;    // 0..4095
    int m = row >> 11, i = row & 2047;
    int K = m ? 13 : 19;
    const float* s = sims + (size_t)m * NN * NN + (size_t)i * NN;
    float sv[32];
    #pragma unroll
    for (int q = 0; q < 8; ++q) {
        float4 v = *((const float4*)&s[q * 256 + (lane << 2)]);
        sv[q * 4 + 0] = v.x; sv[q * 4 + 1] = v.y; sv[q * 4 + 2] = v.z; sv[q * 4 + 3] = v.w;
    }
    float lo = -1.01f, hi = 1.01f;     // cosine sims live in [-1,1]
    for (int it = 0; it < 20; ++it) {
        float t = 0.5f * (lo + hi);
        int cnt = 0;
        #pragma unroll
        for (int r = 0; r < 32; ++r)
            cnt += __popcll(__ballot(sv[r] >= t));
        if (cnt >= K) lo = t; else hi = t;   // wave-uniform branch
    }
    float thr = lo - 1e-5f;
    unsigned long long ltmask = (lane == 0) ? 0ull : ((~0ull) >> (64 - lane));
    int base = 0;
    int* crow = cand + (size_t)row * CANDCAP;
    #pragma unroll
    for (int r = 0; r < 32; ++r) {
        int j = ((r >> 2) << 8) + (lane << 2) + (r & 3);
        bool p = sv[r] >= thr;
        unsigned long long mk = __ballot(p);
        int ofs = base + __popcll(mk & ltmask);
        if (p && ofs < CANDCAP) crow[ofs] = j;
        base += __popcll(mk);
    }
    if (lane == 0) {
        cntb[row] = (base < CANDCAP) ? base : CANDCAP;
        DV[row] = 1;                        // inter-edge contribution
    }
}

// ---------------------------------------------------------------------------
// 4) exact f64 refine + degree count (R10-proven). cnt >= K always; ranks
//    0..cnt-1 distinct => knn rows fully written every call.
// ---------------------------------------------------------------------------
__global__ void k_refine(const double* __restrict__ gR64,
                         const int* __restrict__ cand, const int* __restrict__ cntb,
                         int* __restrict__ knn1, int* __restrict__ knn2,
                         int* __restrict__ DV) {
    __shared__ double dots[CANDCAP];
    int row = blockIdx.x, lane = threadIdx.x;   // 64 threads
    int m = row >> 11, i = row & 2047;
    int K = m ? 13 : 19;
    int cnt = cntb[row]; if (cnt > CANDCAP) cnt = CANDCAP;
    const double* gm = gR64 + (size_t)m * NN * CC;
    const int* crow = cand + (size_t)row * CANDCAP;
    double qc = gm[(size_t)i * CC + lane];
    for (int t = 0; t < cnt; ++t) {
        int j = crow[t];
        double p = qc * gm[(size_t)j * CC + lane];
        #pragma unroll
        for (int d = 32; d >= 1; d >>= 1) p += __shfl_xor(p, d);
        if (lane == 0) dots[t] = p;
    }
    __syncthreads();
    int* knn = m ? knn2 : knn1;
    if (lane < cnt) {
        double vt = dots[lane]; int jt = crow[lane];
        int rank = 0;
        for (int s = 0; s < cnt; ++s) {
            double vs = dots[s]; int js = crow[s];
            if (vs > vt || (vs == vt && js < jt)) ++rank;
        }
        if (rank < K) {
            knn[(size_t)i * K + rank] = jt;
            int w = (rank < (m ? 5 : 7)) ? 2 : 1;   // member of both edges?
            atomicAdd(&DV[m ? NN + jt : jt], w);
        }
    }
}

// ---------------------------------------------------------------------------
// 5) exclusive scan -> CSR offsets for kNN edges only (count = DV[v]-1; the
//    -1 removes the inter edge, which k_node handles inline). dvis uses full
//    DV (includes inter). offs[TWO_N] = 90112.
// ---------------------------------------------------------------------------
__global__ void k_scan(const int* __restrict__ DV, int* __restrict__ offs,
                       int* __restrict__ cursor, double* __restrict__ dvis) {
    int lane = threadIdx.x;      // 64
    int base = lane * 64;
    int s = 0;
    for (int q = 0; q < 64; ++q) s += DV[base + q] - 1;
    int x = s;
    for (int d = 1; d < 64; d <<= 1) {
        int y = __shfl_up(x, d);
        if (lane >= d) x += y;
    }
    int run = x - s;             // exclusive prefix of lane chunk
    for (int q = 0; q < 64; ++q) {
        int v = base + q;
        offs[v] = run; cursor[v] = run;
        dvis[v] = 1.0 / sqrt((double)DV[v]);
        run += DV[v] - 1;
    }
    if (lane == 63) offs[TWO_N] = run;   // == 90112
}

// ---------------------------------------------------------------------------
// 6) fill CSR transpose: node v -> kNN edge ids containing v.
//    families: [0,N) m1k6 ; [N,2N) m1k18 ; [2N,3N) m2k4 ; [3N,4N) m2k12
// ---------------------------------------------------------------------------
__global__ void k_fill(const int* __restrict__ knn1, const int* __restrict__ knn2,
                       int* __restrict__ cursor, int* __restrict__ entries) {
    int id = blockIdx.x * blockDim.x + threadIdx.x;
    const int M1 = NN * 19, M2 = NN * 13;
    if (id < M1) {
        int i = id / 19, t = id % 19;
        int v = knn1[id];
        int p = atomicAdd(&cursor[v], 1); entries[p] = NN + i;       // k=18 edge
        if (t < 7) { int p2 = atomicAdd(&cursor[v], 1); entries[p2] = i; }
    } else if (id < M1 + M2) {
        int id2 = id - M1;
        int i = id2 / 13, t = id2 % 13;
        int v = NN + knn2[id2];
        int p = atomicAdd(&cursor[v], 1); entries[p] = 3 * NN + i;   // k=12 edge
        if (t < 5) { int p2 = atomicAdd(&cursor[v], 1); entries[p2] = 2 * NN + i; }
    }
}

// ---------------------------------------------------------------------------
// 7) y = x @ W1^T (K=64). Register-tiled f64; rows v-major (r' = v*4+b).
// ---------------------------------------------------------------------------
__global__ void __launch_bounds__(256)
k_gemm1(const float* __restrict__ f1, const float* __restrict__ f2,
        const float* __restrict__ W1, float* __restrict__ y) {
    __shared__ double xT[KC][33];    // [k][row] +1 pad
    __shared__ double wT[KC][130];   // [k][col] +2 pad
    int tid = threadIdx.x;
    int g0 = blockIdx.x * 32;        // r' base; 8 nodes x 4 batches per block
    int tr = tid >> 5, tc = tid & 31;
    int r0 = tr * 4;
    double acc[4][4] = {{0.0}};
    for (int kc = 0; kc < CC / KC; ++kc) {
        int k0 = kc * KC;
        __syncthreads();
        #pragma unroll
        for (int q = 0; q < 4; ++q) {          // stage x: 32 rows x 32 k
            int idx = q * 256 + tid;
            int row = idx >> 5, k = idx & 31;
            int rp = g0 + row, v = rp >> 2, b = rp & 3;   // v-major
            const float* src = (v < NN) ? &f1[((size_t)(b * NN) + v) * CC]
                                        : &f2[((size_t)(b * NN) + (v - NN)) * CC];
            xT[k][row] = (double)src[k0 + k];
        }
        #pragma unroll
        for (int q = 0; q < 16; ++q) {         // stage W1: 128 cols x 32 k
            int idx = q * 256 + tid;
            int c = idx >> 5, k = idx & 31;
            wT[k][c] = (double)W1[(size_t)c * CC + k0 + k];
        }
        __syncthreads();
        #pragma unroll
        for (int k = 0; k < KC; ++k) {
            double xr[4], wr[4];
            #pragma unroll
            for (int i = 0; i < 4; ++i) xr[i] = xT[k][r0 + i];
            #pragma unroll
            for (int j = 0; j < 4; ++j) wr[j] = wT[k][tc + 32 * j];
            #pragma unroll
            for (int i = 0; i < 4; ++i)
                #pragma unroll
                for (int j = 0; j < 4; ++j)
                    acc[i][j] += xr[i] * wr[j];
        }
    }
    #pragma unroll
    for (int i = 0; i < 4; ++i)
        #pragma unroll
        for (int j = 0; j < 4; ++j)
            y[(size_t)(g0 + r0 + i) * HD + tc + 32 * j] = (float)acc[i][j];
}

// ---------------------------------------------------------------------------
// 8) y = z @ W2^T (K=128). Same register-tiled structure.
// ---------------------------------------------------------------------------
__global__ void __launch_bounds__(256)
k_gemm2(const float* __restrict__ z, const float* __restrict__ W2,
        float* __restrict__ y) {
    __shared__ double zT[KC][33];
    __shared__ double wT[KC][130];
    int tid = threadIdx.x;
    int g0 = blockIdx.x * 32;
    int tr = tid >> 5, tc = tid & 31;
    int r0 = tr * 4;
    double acc[4][4] = {{0.0}};
    for (int kc = 0; kc < HD / KC; ++kc) {
        int k0 = kc * KC;
        __syncthreads();
        #pragma unroll
        for (int q = 0; q < 4; ++q) {          // stage z: 32 rows x 32 k
            int idx = q * 256 + tid;
            int row = idx >> 5, k = idx & 31;
            zT[k][row] = (double)z[(size_t)(g0 + row) * HD + k0 + k];
        }
        #pragma unroll
        for (int q = 0; q < 16; ++q) {         // stage W2: 128 cols x 32 k
            int idx = q * 256 + tid;
            int c = idx >> 5, k = idx & 31;
            wT[k][c] = (double)W2[(size_t)c * HD + k0 + k];
        }
        __syncthreads();
        #pragma unroll
        for (int k = 0; k < KC; ++k) {
            double zr[4], wr[4];
            #pragma unroll
            for (int i = 0; i < 4; ++i) zr[i] = zT[k][r0 + i];
            #pragma unroll
            for (int j = 0; j < 4; ++j) wr[j] = wT[k][tc + 32 * j];
            #pragma unroll
            for (int i = 0; i < 4; ++i)
                #pragma unroll
                for (int j = 0; j < 4; ++j)
                    acc[i][j] += zr[i] * wr[j];
        }
    }
    #pragma unroll
    for (int i = 0; i < 4; ++i)
        #pragma unroll
        for (int j = 0; j < 4; ++j)
            y[(size_t)(g0 + r0 + i) * HD + tc + 32 * j] = (float)acc[i][j];
}

// ---------------------------------------------------------------------------
// 9) edge stage, PAIRED kNN edges only (prefix-sharing). Grid 2NN:
//    [0,NN) m1 pairs (k6 prefix of k18); [NN,2NN) m2 pairs (k4 prefix of k12).
// ---------------------------------------------------------------------------
__global__ void k_edge(const float4* __restrict__ y4, const double* __restrict__ dvis,
                       const int* __restrict__ knn1, const int* __restrict__ knn2,
                       float4* __restrict__ u4) {
    __shared__ int mem[19];
    __shared__ double wv[19];
    int blk = blockIdx.x;
    int f4 = threadIdx.x & 31;      // float4 feature group
    int b  = threadIdx.x >> 5;      // batch
    int bo = b * 32 + f4;
    int t = threadIdx.x;
    if (blk < NN) {                 // modality-1 pair: k6 (7 members) + k18 (19)
        if (t < 19) { int v = knn1[(size_t)blk * 19 + t]; mem[t] = v; wv[t] = dvis[v]; }
        __syncthreads();
        double ax = 0, ay = 0, az = 0, aw = 0;
        #pragma unroll
        for (int q = 0; q < 7; ++q) {
            double w = wv[q];
            float4 val = y4[(size_t)mem[q] * 128 + bo];
            ax += (double)val.x * w; ay += (double)val.y * w;
            az += (double)val.z * w; aw += (double)val.w * w;
        }
        const double i7 = 1.0 / 49.0;
        u4[(size_t)blk * 128 + bo] =
            make_float4((float)(ax * i7), (float)(ay * i7), (float)(az * i7), (float)(aw * i7));
        #pragma unroll
        for (int q = 7; q < 19; ++q) {
            double w = wv[q];
            float4 val = y4[(size_t)mem[q] * 128 + bo];
            ax += (double)val.x * w; ay += (double)val.y * w;
            az += (double)val.z * w; aw += (double)val.w * w;
        }
        const double i19 = 1.0 / 361.0;
        u4[(size_t)(NN + blk) * 128 + bo] =
            make_float4((float)(ax * i19), (float)(ay * i19), (float)(az * i19), (float)(aw * i19));
    } else {                        // modality-2 pair: k4 (5 members) + k12 (13)
        int i = blk - NN;
        if (t < 13) { int v = NN + knn2[(size_t)i * 13 + t]; mem[t] = v; wv[t] = dvis[v]; }
        __syncthreads();
        double ax = 0, ay = 0, az = 0, aw = 0;
        #pragma unroll
        for (int q = 0; q < 5; ++q) {
            double w = wv[q];
            float4 val = y4[(size_t)mem[q] * 128 + bo];
            ax += (double)val.x * w; ay += (double)val.y * w;
            az += (double)val.z * w; aw += (double)val.w * w;
        }
        const double i5 = 1.0 / 25.0;
        u4[(size_t)(2 * NN + i) * 128 + bo] =
            make_float4((float)(ax * i5), (float)(ay * i5), (float)(az * i5), (float)(aw * i5));
        #pragma unroll
        for (int q = 5; q < 13; ++q) {
            double w = wv[q];
            float4 val = y4[(size_t)mem[q] * 128 + bo];
            ax += (double)val.x * w; ay += (double)val.y * w;
            az += (double)val.z * w; aw += (double)val.w * w;
        }
        const double i13 = 1.0 / 169.0;
        u4[(size_t)(3 * NN + i) * 128 + bo] =
            make_float4((float)(ax * i13), (float)(ay * i13), (float)(az * i13), (float)(aw * i13));
    }
}

// ---------------------------------------------------------------------------
// 10) node stage: z[v,b,f] = relu(dvis[v]*(sum_{e in CSR[v]} u[e,b,f] + inter)).
//     inter edge computed inline (f64): 0.25*(dvis[v]*y[v] + dvis[p]*y[p]).
// ---------------------------------------------------------------------------
__global__ void k_node(const float4* __restrict__ u4, const float4* __restrict__ y4,
                       const double* __restrict__ dvis,
                       const int* __restrict__ offs, const int* __restrict__ entries,
                       float4* __restrict__ zbuf4, float4* __restrict__ outp4, int layer) {
    int v = blockIdx.x;
    int f4 = threadIdx.x & 31;
    int b  = threadIdx.x >> 5;
    int bo = b * 32 + f4;
    int s = offs[v], e_end = offs[v + 1];
    double ax = 0, ay = 0, az = 0, aw = 0;
    double cx = 0, cy = 0, cz = 0, cw = 0;
    int p = s;
    for (; p + 1 < e_end; p += 2) {
        int e0 = entries[p], e1 = entries[p + 1];
        float4 v0 = u4[(size_t)e0 * 128 + bo];
        float4 v1 = u4[(size_t)e1 * 128 + bo];
        ax += v0.x; ay += v0.y; az += v0.z; aw += v0.w;
        cx += v1.x; cy += v1.y; cz += v1.z; cw += v1.w;
    }
    if (p < e_end) {
        float4 v0 = u4[(size_t)entries[p] * 128 + bo];
        ax += v0.x; ay += v0.y; az += v0.z; aw += v0.w;
    }
    ax += cx; ay += cy; az += cz; aw += cw;
    // inline inter edge
    int partner = (v < NN) ? v + NN : v - NN;
    double w0 = dvis[v], w1 = dvis[partner];
    float4 yv = y4[(size_t)v * 128 + bo];
    float4 yp = y4[(size_t)partner * 128 + bo];
    ax += 0.25 * ((double)yv.x * w0 + (double)yp.x * w1);
    ay += 0.25 * ((double)yv.y * w0 + (double)yp.y * w1);
    az += 0.25 * ((double)yv.z * w0 + (double)yp.z * w1);
    aw += 0.25 * ((double)yv.w * w0 + (double)yp.w * w1);
    double dv = w0;
    ax *= dv; ay *= dv; az *= dv; aw *= dv;
    if (ax < 0.0) ax = 0.0;
    if (ay < 0.0) ay = 0.0;
    if (az < 0.0) az = 0.0;
    if (aw < 0.0) aw = 0.0;
    float4 res = make_float4((float)ax, (float)ay, (float)az, (float)aw);
    if (layer == 0) {
        zbuf4[((size_t)v * 4 + b) * 32 + f4] = res;      // v-major
    } else {
        size_t o;
        if (v < NN) o = ((size_t)(b * NN + v)) * 32 + f4;
        else        o = (size_t)BB * NN * 32 + ((size_t)(b * NN + (v - NN))) * 32 + f4;
        outp4[o] = res;
    }
}

// ---------------------------------------------------------------------------
extern "C" void kernel_launch(void* const* d_in, const int* in_sizes, int n_in,
                              void* d_out, int out_size, void* d_ws, size_t ws_size,
                              hipStream_t stream) {
    const float* f1 = (const float*)d_in[0];
    const float* f2 = (const float*)d_in[1];
    const float* W1 = (const float*)d_in[2];
    const float* W2 = (const float*)d_in[3];
    float* out = (float*)d_out;

    // bump allocator over d_ws (~68 MB)
    char* ws = (char*)d_ws;
    size_t off = 0;
    auto alloc = [&](size_t bytes) -> void* {
        void* p = ws + off;
        off = (off + bytes + 255) & ~(size_t)255;
        return p;
    };
    float*  g32T    = (float*)alloc((size_t)2 * CC * NN * 4);         // 1 MB
    double* gR64    = (double*)alloc((size_t)2 * NN * CC * 8);        // 2 MB
    float*  sims    = (float*)alloc((size_t)2 * NN * NN * 4);         // 32 MB
    float*  ybuf    = (float*)alloc((size_t)BB * TWO_N * HD * 4);     // 8 MB  (v-major)
    float*  zbuf    = (float*)alloc((size_t)BB * TWO_N * HD * 4);     // 8 MB  (v-major)
    float*  ubuf    = (float*)alloc((size_t)BB * NE4 * HD * 4);       // 16 MB (e-major)
    double* dvis    = (double*)alloc((size_t)TWO_N * 8);
    int*    knn1    = (int*)alloc((size_t)NN * 19 * 4);
    int*    knn2    = (int*)alloc((size_t)NN * 13 * 4);
    int*    DV      = (int*)alloc((size_t)TWO_N * 4);
    int*    offs    = (int*)alloc((size_t)(TWO_N + 1) * 4);
    int*    cursor  = (int*)alloc((size_t)TWO_N * 4);
    int*    entries = (int*)alloc((size_t)(NN * 26 + NN * 18) * 4);   // 90112
    int*    cand    = (int*)alloc((size_t)TWO_N * CANDCAP * 4);       // 512 KB
    int*    cntb    = (int*)alloc((size_t)TWO_N * 4);

    // graph construction (R10-proven select/refine split)
    k_mean_norm<<<dim3(NN, 2), 64, 0, stream>>>(f1, f2, g32T, gR64);
    k_sims<<<dim3(32 * 32, 2), 256, 0, stream>>>(g32T, sims);
    k_select<<<TWO_N / 8, 512, 0, stream>>>(sims, cand, cntb, DV);
    k_refine<<<TWO_N, 64, 0, stream>>>(gR64, cand, cntb, knn1, knn2, DV);
    k_scan<<<1, 64, 0, stream>>>(DV, offs, cursor, dvis);
    k_fill<<<(NN * 19 + NN * 13 + 255) / 256, 256, 0, stream>>>(knn1, knn2, cursor, entries);

    // layer 1
    k_gemm1<<<(BB * TWO_N) / 32, 256, 0, stream>>>(f1, f2, W1, ybuf);
    k_edge<<<2 * NN, 128, 0, stream>>>((const float4*)ybuf, dvis, knn1, knn2, (float4*)ubuf);
    k_node<<<TWO_N, 128, 0, stream>>>((const float4*)ubuf, (const float4*)ybuf, dvis,
                                      offs, entries, (float4*)zbuf, nullptr, 0);

    // layer 2
    k_gemm2<<<(BB * TWO_N) / 32, 256, 0, stream>>>(zbuf, W2, ybuf);
    k_edge<<<2 * NN, 128, 0, stream>>>((const float4*)ybuf, dvis, knn1, knn2, (float4*)ubuf);
    k_node<<<TWO_N, 128, 0, stream>>>((const float4*)ubuf, (const float4*)ybuf, dvis,
                                      offs, entries, nullptr, (float4*)out, 1);
}

// Round 13
// 239.833 us; speedup vs baseline: 1.0201x; 1.0201x over previous
//
#include <hip/hip_runtime.h>
#include <math.h>

// Problem constants
#define NN 2048      // nodes per modality
#define TWO_N 4096   // total nodes
#define BB 4         // batch
#define CC 64        // input feature dim
#define HD 128       // hidden dim
#define CANDCAP 32   // max top-k candidates per row after f32 margin filter
#define KC 32        // gemm K-chunk
#define NE4 (4 * NN) // materialized hyperedges (inter edges handled inline in k_node)

// Layouts: y/z are v-major [v][b][f] (row r' = v*4+b); u is [e][b][f], e in [0,4N).

// ---------------------------------------------------------------------------
// 1) batch-mean + L2-normalize. Also zeroes DV (prior launch => no race with
//    k_selref's atomicAdds; inter-edge +1 handled analytically in k_scan).
// ---------------------------------------------------------------------------
__global__ void k_mean_norm(const float* __restrict__ f1, const float* __restrict__ f2,
                            float* __restrict__ g32T, double* __restrict__ gR64,
                            int* __restrict__ DV) {
    int n = blockIdx.x;           // node
    int m = blockIdx.y;           // modality
    int c = threadIdx.x;          // 64 threads = 1 wave
    if (m == 0 && n < 64) DV[n * 64 + c] = 0;   // covers 0..4095
    const float* f = m ? f2 : f1;
    double s = 0.0;
    for (int b = 0; b < BB; ++b) s += (double)f[((size_t)(b * NN) + n) * CC + c];
    double mean = s * 0.25;
    double sq = mean * mean;
    for (int d = 32; d >= 1; d >>= 1) sq += __shfl_xor(sq, d);
    double norm = sqrt(sq);
    if (norm < 1e-12) norm = 1e-12;
    double g = mean / norm;
    g32T[((size_t)m * CC + c) * NN + n] = (float)g;
    gR64[((size_t)m * NN + n) * CC + c] = g;
}

// ---------------------------------------------------------------------------
// 2) f32 sims GEMM, symmetric: compute upper-triangle tiles only (bi<=bj),
//    mirror-write the transpose via LDS bounce. Lower-triangle blocks exit
//    before any barrier (uniform). Diagonal writes twice with equal values.
// ---------------------------------------------------------------------------
__global__ void __launch_bounds__(256)
k_sims(const float* __restrict__ g32T, float* __restrict__ sims) {
    __shared__ float As[CC][64];   // 16 KB
    __shared__ float Bs[CC][64];   // 16 KB
    __shared__ float Cs[64][65];   // 16.25 KB tile bounce (stride 65: no conflicts)
    int m  = blockIdx.y;
    int bi = blockIdx.x >> 5, bj = blockIdx.x & 31;
    if (bi > bj) return;           // symmetric: skip lower triangle
    int i0 = bi * 64, j0 = bj * 64;
    const float* g = g32T + (size_t)m * CC * NN;
    int tid = threadIdx.x;
    #pragma unroll
    for (int q = 0; q < 16; ++q) {
        int idx = q * 256 + tid;
        int k = idx >> 6, r = idx & 63;
        As[k][r] = g[(size_t)k * NN + i0 + r];
        Bs[k][r] = g[(size_t)k * NN + j0 + r];
    }
    __syncthreads();
    int tr = tid >> 4, tc = tid & 15;
    float acc[4][4] = {{0.f}};
    #pragma unroll
    for (int k = 0; k < CC; ++k) {
        float4 a = *((const float4*)&As[k][tr << 2]);
        float4 b = *((const float4*)&Bs[k][tc << 2]);
        acc[0][0] += a.x * b.x; acc[0][1] += a.x * b.y; acc[0][2] += a.x * b.z; acc[0][3] += a.x * b.w;
        acc[1][0] += a.y * b.x; acc[1][1] += a.y * b.y; acc[1][2] += a.y * b.z; acc[1][3] += a.y * b.w;
        acc[2][0] += a.z * b.x; acc[2][1] += a.z * b.y; acc[2][2] += a.z * b.z; acc[2][3] += a.z * b.w;
        acc[3][0] += a.w * b.x; acc[3][1] += a.w * b.y; acc[3][2] += a.w * b.z; acc[3][3] += a.w * b.w;
    }
    float* srow = sims + (size_t)m * NN * NN;
    // direct write + stage into LDS for the mirror
    #pragma unroll
    for (int x = 0; x < 4; ++x) {
        float4 v = make_float4(acc[x][0], acc[x][1], acc[x][2], acc[x][3]);
        *((float4*)&srow[(size_t)(i0 + (tr << 2) + x) * NN + j0 + (tc << 2)]) = v;
        Cs[(tr << 2) + x][(tc << 2) + 0] = acc[x][0];
        Cs[(tr << 2) + x][(tc << 2) + 1] = acc[x][1];
        Cs[(tr << 2) + x][(tc << 2) + 2] = acc[x][2];
        Cs[(tr << 2) + x][(tc << 2) + 3] = acc[x][3];
    }
    __syncthreads();
    // mirror write: sims[j0+cc][i0+rr] = Cs[rr][cc]
    #pragma unroll
    for (int q = 0; q < 4; ++q) {
        int idx = q * 256 + tid;
        int cc = idx >> 4, rr4 = (idx & 15) << 2;
        float4 v = make_float4(Cs[rr4 + 0][cc], Cs[rr4 + 1][cc],
                               Cs[rr4 + 2][cc], Cs[rr4 + 3][cc]);
        *((float4*)&srow[(size_t)(j0 + cc) * NN + i0 + rr4]) = v;
    }
}

// ---------------------------------------------------------------------------
// 3) FUSED select+refine (R11 structure, barrier bug FIXED):
//    f32 threshold via binary-search ballot; candidates -> LDS;
//    __syncthreads(); exact f64 dots -> LDS; __syncthreads(); rank + write.
//    thr = lo - 1e-5 <= vK_f32 - 2*eps => cand superset of true f64 top-K.
//    DV: atomicAdd only (zeroed in k_mean_norm; no init-store race).
// ---------------------------------------------------------------------------
__global__ void __launch_bounds__(512)
k_selref(const float* __restrict__ sims, const double* __restrict__ gR64,
         int* __restrict__ knn1, int* __restrict__ knn2, int* __restrict__ DV) {
    __shared__ int    candL[8][CANDCAP];
    __shared__ double dotsL[8][CANDCAP];
    int wave = threadIdx.x >> 6, lane = threadIdx.x & 63;
    int row = blockIdx.x * 8 + wave;    // 0..4095
    int m = row >> 11, i = row & 2047;
    int K = m ? 13 : 19;
    const float* s = sims + (size_t)m * NN * NN + (size_t)i * NN;
    float sv[32];
    #pragma unroll
    for (int q = 0; q < 8; ++q) {
        float4 v = *((const float4*)&s[q * 256 + (lane << 2)]);
        sv[q * 4 + 0] = v.x; sv[q * 4 + 1] = v.y; sv[q * 4 + 2] = v.z; sv[q * 4 + 3] = v.w;
    }
    float lo = -1.01f, hi = 1.01f;     // cosine sims live in [-1,1]
    for (int it = 0; it < 20; ++it) {
        float t = 0.5f * (lo + hi);
        int cnt = 0;
        #pragma unroll
        for (int r = 0; r < 32; ++r)
            cnt += __popcll(__ballot(sv[r] >= t));
        if (cnt >= K) lo = t; else hi = t;   // wave-uniform branch
    }
    float thr = lo - 1e-5f;
    unsigned long long ltmask = (lane == 0) ? 0ull : ((~0ull) >> (64 - lane));
    int base = 0;
    #pragma unroll
    for (int r = 0; r < 32; ++r) {
        int j = ((r >> 2) << 8) + (lane << 2) + (r & 3);
        bool p = sv[r] >= thr;
        unsigned long long mk = __ballot(p);
        int ofs = base + __popcll(mk & ltmask);
        if (p && ofs < CANDCAP) candL[wave][ofs] = j;
        base += __popcll(mk);
    }
    int cnt = (base < CANDCAP) ? base : CANDCAP;
    __syncthreads();                       // candL visible (was the R11 bug)
    const double* gm = gR64 + (size_t)m * NN * CC;
    double qc = gm[(size_t)i * CC + lane];
    for (int t = 0; t < cnt; ++t) {
        int j = candL[wave][t];
        double p = qc * gm[(size_t)j * CC + lane];
        #pragma unroll
        for (int d = 32; d >= 1; d >>= 1) p += __shfl_xor(p, d);
        if (lane == 0) dotsL[wave][t] = p;
    }
    __syncthreads();                       // dotsL visible
    int* knn = m ? knn2 : knn1;
    if (lane < cnt) {
        double vt = dotsL[wave][lane]; int jt = candL[wave][lane];
        int rank = 0;
        for (int s2 = 0; s2 < cnt; ++s2) {
            double vs = dotsL[wave][s2]; int js = candL[wave][s2];
            if (vs > vt || (vs == vt && js < jt)) ++rank;
        }
        if (rank < K) {
            knn[(size_t)i * K + rank] = jt;
            int w = (rank < (m ? 5 : 7)) ? 2 : 1;   // member of both edges?
            atomicAdd(&DV[m ? NN + jt : jt], w);
        }
    }
}

// ---------------------------------------------------------------------------
// 4) exclusive scan -> CSR offsets (kNN edges; DV excludes inter).
//    dvis = 1/sqrt(DV+1) (the +1 is the inter edge, inlined in k_node).
// ---------------------------------------------------------------------------
__global__ void k_scan(const int* __restrict__ DV, int* __restrict__ offs,
                       int* __restrict__ cursor, double* __restrict__ dvis) {
    int lane = threadIdx.x;      // 64
    int base = lane * 64;
    int s = 0;
    for (int q = 0; q < 64; ++q) s += DV[base + q];
    int x = s;
    for (int d = 1; d < 64; d <<= 1) {
        int y = __shfl_up(x, d);
        if (lane >= d) x += y;
    }
    int run = x - s;             // exclusive prefix of lane chunk
    for (int q = 0; q < 64; ++q) {
        int v = base + q;
        offs[v] = run; cursor[v] = run;
        dvis[v] = 1.0 / sqrt((double)(DV[v] + 1));
        run += DV[v];
    }
    if (lane == 63) offs[TWO_N] = run;   // == 90112
}

// ---------------------------------------------------------------------------
// 5) fill CSR transpose: node v -> kNN edge ids containing v.
//    families: [0,N) m1k6 ; [N,2N) m1k18 ; [2N,3N) m2k4 ; [3N,4N) m2k12
// ---------------------------------------------------------------------------
__global__ void k_fill(const int* __restrict__ knn1, const int* __restrict__ knn2,
                       int* __restrict__ cursor, int* __restrict__ entries) {
    int id = blockIdx.x * blockDim.x + threadIdx.x;
    const int M1 = NN * 19, M2 = NN * 13;
    if (id < M1) {
        int i = id / 19, t = id % 19;
        int v = knn1[id];
        int p = atomicAdd(&cursor[v], 1); entries[p] = NN + i;       // k=18 edge
        if (t < 7) { int p2 = atomicAdd(&cursor[v], 1); entries[p2] = i; }
    } else if (id < M1 + M2) {
        int id2 = id - M1;
        int i = id2 / 13, t = id2 % 13;
        int v = NN + knn2[id2];
        int p = atomicAdd(&cursor[v], 1); entries[p] = 3 * NN + i;   // k=12 edge
        if (t < 5) { int p2 = atomicAdd(&cursor[v], 1); entries[p2] = 2 * NN + i; }
    }
}

// ---------------------------------------------------------------------------
// 6) y = x @ W1^T (K=64). Register-tiled f64; rows v-major (r' = v*4+b).
// ---------------------------------------------------------------------------
__global__ void __launch_bounds__(256)
k_gemm1(const float* __restrict__ f1, const float* __restrict__ f2,
        const float* __restrict__ W1, float* __restrict__ y) {
    __shared__ double xT[KC][33];    // [k][row] +1 pad
    __shared__ double wT[KC][130];   // [k][col] +2 pad
    int tid = threadIdx.x;
    int g0 = blockIdx.x * 32;        // r' base; 8 nodes x 4 batches per block
    int tr = tid >> 5, tc = tid & 31;
    int r0 = tr * 4;
    double acc[4][4] = {{0.0}};
    for (int kc = 0; kc < CC / KC; ++kc) {
        int k0 = kc * KC;
        __syncthreads();
        #pragma unroll
        for (int q = 0; q < 4; ++q) {          // stage x: 32 rows x 32 k
            int idx = q * 256 + tid;
            int row = idx >> 5, k = idx & 31;
            int rp = g0 + row, v = rp >> 2, b = rp & 3;   // v-major
            const float* src = (v < NN) ? &f1[((size_t)(b * NN) + v) * CC]
                                        : &f2[((size_t)(b * NN) + (v - NN)) * CC];
            xT[k][row] = (double)src[k0 + k];
        }
        #pragma unroll
        for (int q = 0; q < 16; ++q) {         // stage W1: 128 cols x 32 k
            int idx = q * 256 + tid;
            int c = idx >> 5, k = idx & 31;
            wT[k][c] = (double)W1[(size_t)c * CC + k0 + k];
        }
        __syncthreads();
        #pragma unroll
        for (int k = 0; k < KC; ++k) {
            double xr[4], wr[4];
            #pragma unroll
            for (int i = 0; i < 4; ++i) xr[i] = xT[k][r0 + i];
            #pragma unroll
            for (int j = 0; j < 4; ++j) wr[j] = wT[k][tc + 32 * j];
            #pragma unroll
            for (int i = 0; i < 4; ++i)
                #pragma unroll
                for (int j = 0; j < 4; ++j)
                    acc[i][j] += xr[i] * wr[j];
        }
    }
    #pragma unroll
    for (int i = 0; i < 4; ++i)
        #pragma unroll
        for (int j = 0; j < 4; ++j)
            y[(size_t)(g0 + r0 + i) * HD + tc + 32 * j] = (float)acc[i][j];
}

// ---------------------------------------------------------------------------
// 7) y = z @ W2^T (K=128). Same register-tiled structure.
// ---------------------------------------------------------------------------
__global__ void __launch_bounds__(256)
k_gemm2(const float* __restrict__ z, const float* __restrict__ W2,
        float* __restrict__ y) {
    __shared__ double zT[KC][33];
    __shared__ double wT[KC][130];
    int tid = threadIdx.x;
    int g0 = blockIdx.x * 32;
    int tr = tid >> 5, tc = tid & 31;
    int r0 = tr * 4;
    double acc[4][4] = {{0.0}};
    for (int kc = 0; kc < HD / KC; ++kc) {
        int k0 = kc * KC;
        __syncthreads();
        #pragma unroll
        for (int q = 0; q < 4; ++q) {          // stage z: 32 rows x 32 k
            int idx = q * 256 + tid;
            int row = idx >> 5, k = idx & 31;
            zT[k][row] = (double)z[(size_t)(g0 + row) * HD + k0 + k];
        }
        #pragma unroll
        for (int q = 0; q < 16; ++q) {         // stage W2: 128 cols x 32 k
            int idx = q * 256 + tid;
            int c = idx >> 5, k = idx & 31;
            wT[k][c] = (double)W2[(size_t)c * HD + k0 + k];
        }
        __syncthreads();
        #pragma unroll
        for (int k = 0; k < KC; ++k) {
            double zr[4], wr[4];
            #pragma unroll
            for (int i = 0; i < 4; ++i) zr[i] = zT[k][r0 + i];
            #pragma unroll
            for (int j = 0; j < 4; ++j) wr[j] = wT[k][tc + 32 * j];
            #pragma unroll
            for (int i = 0; i < 4; ++i)
                #pragma unroll
                for (int j = 0; j < 4; ++j)
                    acc[i][j] += zr[i] * wr[j];
        }
    }
    #pragma unroll
    for (int i = 0; i < 4; ++i)
        #pragma unroll
        for (int j = 0; j < 4; ++j)
            y[(size_t)(g0 + r0 + i) * HD + tc + 32 * j] = (float)acc[i][j];
}

// ---------------------------------------------------------------------------
// 8) edge stage, PAIRED kNN edges only (prefix-sharing). Grid 2NN.
// ---------------------------------------------------------------------------
__global__ void k_edge(const float4* __restrict__ y4, const double* __restrict__ dvis,
                       const int* __restrict__ knn1, const int* __restrict__ knn2,
                       float4* __restrict__ u4) {
    __shared__ int mem[19];
    __shared__ double wv[19];
    int blk = blockIdx.x;
    int f4 = threadIdx.x & 31;      // float4 feature group
    int b  = threadIdx.x >> 5;      // batch
    int bo = b * 32 + f4;
    int t = threadIdx.x;
    if (blk < NN) {                 // modality-1 pair: k6 (7 members) + k18 (19)
        if (t < 19) { int v = knn1[(size_t)blk * 19 + t]; mem[t] = v; wv[t] = dvis[v]; }
        __syncthreads();
        double ax = 0, ay = 0, az = 0, aw = 0;
        #pragma unroll
        for (int q = 0; q < 7; ++q) {
            double w = wv[q];
            float4 val = y4[(size_t)mem[q] * 128 + bo];
            ax += (double)val.x * w; ay += (double)val.y * w;
            az += (double)val.z * w; aw += (double)val.w * w;
        }
        const double i7 = 1.0 / 49.0;
        u4[(size_t)blk * 128 + bo] =
            make_float4((float)(ax * i7), (float)(ay * i7), (float)(az * i7), (float)(aw * i7));
        #pragma unroll
        for (int q = 7; q < 19; ++q) {
            double w = wv[q];
            float4 val = y4[(size_t)mem[q] * 128 + bo];
            ax += (double)val.x * w; ay += (double)val.y * w;
            az += (double)val.z * w; aw += (double)val.w * w;
        }
        const double i19 = 1.0 / 361.0;
        u4[(size_t)(NN + blk) * 128 + bo] =
            make_float4((float)(ax * i19), (float)(ay * i19), (float)(az * i19), (float)(aw * i19));
    } else {                        // modality-2 pair: k4 (5 members) + k12 (13)
        int i = blk - NN;
        if (t < 13) { int v = NN + knn2[(size_t)i * 13 + t]; mem[t] = v; wv[t] = dvis[v]; }
        __syncthreads();
        double ax = 0, ay = 0, az = 0, aw = 0;
        #pragma unroll
        for (int q = 0; q < 5; ++q) {
            double w = wv[q];
            float4 val = y4[(size_t)mem[q] * 128 + bo];
            ax += (double)val.x * w; ay += (double)val.y * w;
            az += (double)val.z * w; aw += (double)val.w * w;
        }
        const double i5 = 1.0 / 25.0;
        u4[(size_t)(2 * NN + i) * 128 + bo] =
            make_float4((float)(ax * i5), (float)(ay * i5), (float)(az * i5), (float)(aw * i5));
        #pragma unroll
        for (int q = 5; q < 13; ++q) {
            double w = wv[q];
            float4 val = y4[(size_t)mem[q] * 128 + bo];
            ax += (double)val.x * w; ay += (double)val.y * w;
            az += (double)val.z * w; aw += (double)val.w * w;
        }
        const double i13 = 1.0 / 169.0;
        u4[(size_t)(3 * NN + i) * 128 + bo] =
            make_float4((float)(ax * i13), (float)(ay * i13), (float)(az * i13), (float)(aw * i13));
    }
}

// ---------------------------------------------------------------------------
// 9) node stage: z[v,b,f] = relu(dvis[v]*(sum_{e in CSR[v]} u[e,b,f] + inter)).
//    4-way unrolled gather (4 independent f64 chains); inter edge inline.
// ---------------------------------------------------------------------------
__global__ void k_node(const float4* __restrict__ u4, const float4* __restrict__ y4,
                       const double* __restrict__ dvis,
                       const int* __restrict__ offs, const int* __restrict__ entries,
                       float4* __restrict__ zbuf4, float4* __restrict__ outp4, int layer) {
    int v = blockIdx.x;
    int f4 = threadIdx.x & 31;
    int b  = threadIdx.x >> 5;
    int bo = b * 32 + f4;
    int s = offs[v], e_end = offs[v + 1];
    double a0x = 0, a0y = 0, a0z = 0, a0w = 0;
    double a1x = 0, a1y = 0, a1z = 0, a1w = 0;
    double a2x = 0, a2y = 0, a2z = 0, a2w = 0;
    double a3x = 0, a3y = 0, a3z = 0, a3w = 0;
    int p = s;
    for (; p + 3 < e_end; p += 4) {
        int e0 = entries[p], e1 = entries[p + 1], e2 = entries[p + 2], e3 = entries[p + 3];
        float4 v0 = u4[(size_t)e0 * 128 + bo];
        float4 v1 = u4[(size_t)e1 * 128 + bo];
        float4 v2 = u4[(size_t)e2 * 128 + bo];
        float4 v3 = u4[(size_t)e3 * 128 + bo];
        a0x += v0.x; a0y += v0.y; a0z += v0.z; a0w += v0.w;
        a1x += v1.x; a1y += v1.y; a1z += v1.z; a1w += v1.w;
        a2x += v2.x; a2y += v2.y; a2z += v2.z; a2w += v2.w;
        a3x += v3.x; a3y += v3.y; a3z += v3.z; a3w += v3.w;
    }
    for (; p < e_end; ++p) {
        float4 v0 = u4[(size_t)entries[p] * 128 + bo];
        a0x += v0.x; a0y += v0.y; a0z += v0.z; a0w += v0.w;
    }
    double ax = (a0x + a1x) + (a2x + a3x);
    double ay = (a0y + a1y) + (a2y + a3y);
    double az = (a0z + a1z) + (a2z + a3z);
    double aw = (a0w + a1w) + (a2w + a3w);
    // inline inter edge
    int partner = (v < NN) ? v + NN : v - NN;
    double w0 = dvis[v], w1 = dvis[partner];
    float4 yv = y4[(size_t)v * 128 + bo];
    float4 yp = y4[(size_t)partner * 128 + bo];
    ax += 0.25 * ((double)yv.x * w0 + (double)yp.x * w1);
    ay += 0.25 * ((double)yv.y * w0 + (double)yp.y * w1);
    az += 0.25 * ((double)yv.z * w0 + (double)yp.z * w1);
    aw += 0.25 * ((double)yv.w * w0 + (double)yp.w * w1);
    ax *= w0; ay *= w0; az *= w0; aw *= w0;
    if (ax < 0.0) ax = 0.0;
    if (ay < 0.0) ay = 0.0;
    if (az < 0.0) az = 0.0;
    if (aw < 0.0) aw = 0.0;
    float4 res = make_float4((float)ax, (float)ay, (float)az, (float)aw);
    if (layer == 0) {
        zbuf4[((size_t)v * 4 + b) * 32 + f4] = res;      // v-major
    } else {
        size_t o;
        if (v < NN) o = ((size_t)(b * NN + v)) * 32 + f4;
        else        o = (size_t)BB * NN * 32 + ((size_t)(b * NN + (v - NN))) * 32 + f4;
        outp4[o] = res;
    }
}

// ---------------------------------------------------------------------------
extern "C" void kernel_launch(void* const* d_in, const int* in_sizes, int n_in,
                              void* d_out, int out_size, void* d_ws, size_t ws_size,
                              hipStream_t stream) {
    const float* f1 = (const float*)d_in[0];
    const float* f2 = (const float*)d_in[1];
    const float* W1 = (const float*)d_in[2];
    const float* W2 = (const float*)d_in[3];
    float* out = (float*)d_out;

    // bump allocator over d_ws (~68 MB)
    char* ws = (char*)d_ws;
    size_t off = 0;
    auto alloc = [&](size_t bytes) -> void* {
        void* p = ws + off;
        off = (off + bytes + 255) & ~(size_t)255;
        return p;
    };
    float*  g32T    = (float*)alloc((size_t)2 * CC * NN * 4);         // 1 MB
    double* gR64    = (double*)alloc((size_t)2 * NN * CC * 8);        // 2 MB
    float*  sims    = (float*)alloc((size_t)2 * NN * NN * 4);         // 32 MB
    float*  ybuf    = (float*)alloc((size_t)BB * TWO_N * HD * 4);     // 8 MB  (v-major)
    float*  zbuf    = (float*)alloc((size_t)BB * TWO_N * HD * 4);     // 8 MB  (v-major)
    float*  ubuf    = (float*)alloc((size_t)BB * NE4 * HD * 4);       // 16 MB (e-major)
    double* dvis    = (double*)alloc((size_t)TWO_N * 8);
    int*    knn1    = (int*)alloc((size_t)NN * 19 * 4);
    int*    knn2    = (int*)alloc((size_t)NN * 13 * 4);
    int*    DV      = (int*)alloc((size_t)TWO_N * 4);
    int*    offs    = (int*)alloc((size_t)(TWO_N + 1) * 4);
    int*    cursor  = (int*)alloc((size_t)TWO_N * 4);
    int*    entries = (int*)alloc((size_t)(NN * 26 + NN * 18) * 4);   // 90112

    // graph construction
    k_mean_norm<<<dim3(NN, 2), 64, 0, stream>>>(f1, f2, g32T, gR64, DV);
    k_sims<<<dim3(32 * 32, 2), 256, 0, stream>>>(g32T, sims);
    k_selref<<<TWO_N / 8, 512, 0, stream>>>(sims, gR64, knn1, knn2, DV);
    k_scan<<<1, 64, 0, stream>>>(DV, offs, cursor, dvis);
    k_fill<<<(NN * 19 + NN * 13 + 255) / 256, 256, 0, stream>>>(knn1, knn2, cursor, entries);

    // layer 1
    k_gemm1<<<(BB * TWO_N) / 32, 256, 0, stream>>>(f1, f2, W1, ybuf);
    k_edge<<<2 * NN, 128, 0, stream>>>((const float4*)ybuf, dvis, knn1, knn2, (float4*)ubuf);
    k_node<<<TWO_N, 128, 0, stream>>>((const float4*)ubuf, (const float4*)ybuf, dvis,
                                      offs, entries, (float4*)zbuf, nullptr, 0);

    // layer 2
    k_gemm2<<<(BB * TWO_N) / 32, 256, 0, stream>>>(zbuf, W2, ybuf);
    k_edge<<<2 * NN, 128, 0, stream>>>((const float4*)ybuf, dvis, knn1, knn2, (float4*)ubuf);
    k_node<<<TWO_N, 128, 0, stream>>>((const float4*)ubuf, (const float4*)ybuf, dvis,
                                      offs, entries, nullptr, (float4*)out, 1);
}